// Round 7
// baseline (245.909 us; speedup 1.0000x reference)
//
#include <hip/hip_runtime.h>
#include <math.h>

typedef _Float16 half_t;
typedef __attribute__((ext_vector_type(8))) _Float16 half8;
typedef __attribute__((ext_vector_type(4))) _Float16 half4;
typedef __attribute__((ext_vector_type(4))) float floatx4;

#define TDIM 36
#define PDIM 161        // 2*80+1 atoms
#define NCOL 50
#define NITER 100
#define PITER8 50       // power steps on G^8 == 400 on G (same total as proven config)

// ATOM PERMUTATION: LDS slot s in [0,160) holds atom s+1; the constant atom (p=0)
// is folded out of both GEMMs (phase A: scalar -y0; phase B: column-sum of R).
// phase A: M=48,N=64,K=160 (5 ks), 12 waves = 3 mt x 4 nt
//   R pad rows t>=36 are explicitly ZEROED (R6 bug: they held -y0 and leaked
//   into the constant-atom column-sum).
// phase B: M=160 (10 pt),N=64,K=64; wave (g=w>>1,h=w&1) owns pt in {g,g+6}(<10),
//          stripes {2h,2h+1}. Dt frags = 32 VGPR (R5's 64 spilled -> scratch).
//          g==5 waves also run the constant-atom column-sum from their rb frags.
#define NKA 5
#define GSTR 44
#define SPS 196         // Df (fp32) row stride (dwords)

// row strides in BYTES
#define YROW 384        // y^T [64][slots 0..159] half (+swizzle headroom)
#define RROW 128        // R^T [64][64] half

// XOR swizzle: spread same-column reads across 8 rows -> 8 distinct 16B slots
#define SWZ(row, byteoff) ((byteoff) ^ (((row) & 7) << 4))

// ---- byte-offset LDS map: 52,048 B ----
#define BY_Y    0                      // 24,576
#define BY_R    24576                  //  8,192
#define BY_LRTH 28672                  //  1,288 (inside R region, past Df end 28,224)
#define BY_Y0   32768                  //    256 (fp32 y/x for the constant atom)
#define BY_SC   33024                  //     16
#define BY_GS   33040                  //  6,336
#define BY_G2   39376                  //  6,336  (holds G^2, later overwritten by G^8)
#define BY_G4   45712                  //  6,336
#define LDS_TOTAL 52048
// setup alias: Df fp32 [36][196] = 28,224 B over Y + head of R (re-zeroed before loop)

#define MFMA16 __builtin_amdgcn_mfma_f32_16x16x32_f16

__global__ __launch_bounds__(768, 3)
void dan_kernel(const float* __restrict__ xin, const float* __restrict__ rho,
                const float* __restrict__ theta, float* __restrict__ outC,
                float* __restrict__ outDic, float* __restrict__ outR)
{
  extern __shared__ char smc[];
  float*  sc   = (float*)(smc + BY_SC);
  float*  Gs   = (float*)(smc + BY_GS);
  float*  G2   = (float*)(smc + BY_G2);
  float*  G4   = (float*)(smc + BY_G4);
  float*  Y0f  = (float*)(smc + BY_Y0);
  float*  Df   = (float*)(smc + BY_Y);    // setup alias
  float*  lrth = (float*)(smc + BY_LRTH); // [161] lr, [161] th (setup only)

  const int tid = threadIdx.x;
  const int b = blockIdx.x;
  const int wave = tid >> 6, lane = tid & 63;
  const int q = lane >> 4, ln = lane & 15;

  // ---- A. zero all LDS (pads must be 0)
  {
    unsigned int* z = (unsigned int*)smc;
    for (int i = tid; i < LDS_TOTAL / 4; i += 768) z[i] = 0u;
  }
  __syncthreads();

  // ---- B0. per-atom lr/th (161 threads, 2 transcendentals each)
  if (tid >= 1 && tid < PDIM) {
    const bool is_sin = tid > 80;
    const int n = is_sin ? (tid - 81) : (tid - 1);
    lrth[tid]       = logf(0.001f + 1.149f / (1.0f + expf(-rho[n])));
    lrth[161 + tid] = 3.14159265358979f / (1.0f + expf(-theta[n]));
  }
  __syncthreads();

  // ---- B1. raw dictionary, parallel over all (t,p) jobs
  for (int i = tid; i < TDIM * PDIM; i += 768) {
    const int t = i / PDIM, p = i - t * PDIM;
    float val;
    if (p == 0) {
      val = 1.0f;
    } else {
      const float ft = (float)t;
      const float e = expf(ft * lrth[p]);
      const float ang = ft * lrth[161 + p];
      val = e * (p > 80 ? sinf(ang) : cosf(ang));
    }
    Df[t * SPS + p] = val;
  }
  __syncthreads();

  // ---- B2. column-normalize (atoms 1..160)
  if (tid >= 1 && tid < PDIM) {
    float s2 = 0.0f;
    for (int t = 0; t < TDIM; ++t) {
      const float v = Df[t * SPS + tid];
      s2 += v * v;
    }
    const float inv = 1.0f / sqrtf(s2);
    for (int t = 0; t < TDIM; ++t) Df[t * SPS + tid] *= inv;
  }
  __syncthreads();

  // ---- C. Gram -> Gs ; dic out ; load ALL MFMA fragments to registers
  if (tid < 666) {                      // 666 = 36*37/2
    int i = 0, rem = tid;
    while (rem >= TDIM - i) { rem -= TDIM - i; ++i; }
    const int j = i + rem;
    const float4* ri = (const float4*)(Df + i * SPS);
    const float4* rj = (const float4*)(Df + j * SPS);
    float a = 0.0f;
    #pragma unroll 7
    for (int k = 0; k < SPS / 4; ++k) {
      const float4 x = ri[k], y = rj[k];
      a += x.x * y.x + x.y * y.y + x.z * y.z + x.w * y.w;
    }
    Gs[i * GSTR + j] = a;
    Gs[j * GSTR + i] = a;
  }
  if (b == 0) {
    for (int i = tid; i < TDIM * PDIM; i += 768) {
      const int t = i / PDIM, p = i - t * PDIM;
      outDic[i] = Df[t * SPS + p];
    }
  }

  // ownership maps
  const int mtA = wave >> 2;            // phase A: 3 mt x 4 nt, one tile per wave
  const int ntA = wave & 3;
  const int g = wave >> 1;              // phase B: pt in {g, g+6} (valid < 10)
  const int h = wave & 1;               //          stripes {2h, 2h+1}

  // phase-A A-fragments (D hi/lo), atoms 1..160 in K-slots 0..159; rows >= 36 zero
  half8 DhF[NKA], DlF[NKA];
  {
    const int row = 16 * mtA + ln;
    #pragma unroll
    for (int ks = 0; ks < NKA; ++ks) {
      half8 hh, ll;
      #pragma unroll
      for (int e = 0; e < 8; ++e) {
        const int p = 32 * ks + 8 * q + e + 1;      // atom 1..160
        const float v = (row < TDIM) ? Df[row * SPS + p] : 0.0f;
        const half_t h2 = (half_t)v;
        hh[e] = h2;
        ll[e] = (half_t)(v - (float)h2);
      }
      DhF[ks] = hh;
      DlF[ks] = ll;
    }
  }
  // phase-B A-fragments (D^T hi/lo) for this wave's 2 pt tiles (slot s = atom s+1)
  half8 DtH[2][2], DtL[2][2];
  #pragma unroll
  for (int k = 0; k < 2; ++k) {
    const int pt = g + 6 * k;
    if (pt < 10) {
      const int atom = 16 * pt + ln + 1;            // 1..160
      #pragma unroll
      for (int ks = 0; ks < 2; ++ks) {
        half8 hh, ll;
        #pragma unroll
        for (int e = 0; e < 8; ++e) {
          const int t = 32 * ks + 8 * q + e;
          const float v = (t < TDIM) ? Df[t * SPS + atom] : 0.0f;
          const half_t h2 = (half_t)v;
          hh[e] = h2;
          ll[e] = (half_t)(v - (float)h2);
        }
        DtH[k][ks] = hh;
        DtL[k][ks] = ll;
      }
    }
  }
  // static Y (fp32) at phase-A C positions
  float yA[4];
  {
    const float* xb = xin + b * TDIM * NCOL;
    const int c = 16 * ntA + ln;
    #pragma unroll
    for (int r = 0; r < 4; ++r) {
      const int t = 16 * mtA + 4 * q + r;
      yA[r] = (t < TDIM && c < NCOL) ? xb[t * NCOL + c] : 0.0f;
    }
  }
  __syncthreads();

  // ---- C2. G2 = G*G  (pads of all Gram buffers are zero)
  if (tid < 666) {
    int i = 0, rem = tid;
    while (rem >= TDIM - i) { rem -= TDIM - i; ++i; }
    const int j = i + rem;
    const float4* ri = (const float4*)(Gs + i * GSTR);
    const float4* rj = (const float4*)(Gs + j * GSTR);
    float a = 0.0f;
    #pragma unroll
    for (int k = 0; k < GSTR / 4; ++k) {
      const float4 x = ri[k], y = rj[k];
      a += x.x * y.x + x.y * y.y + x.z * y.z + x.w * y.w;
    }
    G2[i * GSTR + j] = a;
    G2[j * GSTR + i] = a;
  }
  __syncthreads();
  // ---- C3. G4 = G2*G2
  if (tid < 666) {
    int i = 0, rem = tid;
    while (rem >= TDIM - i) { rem -= TDIM - i; ++i; }
    const int j = i + rem;
    const float4* ri = (const float4*)(G2 + i * GSTR);
    const float4* rj = (const float4*)(G2 + j * GSTR);
    float a = 0.0f;
    #pragma unroll
    for (int k = 0; k < GSTR / 4; ++k) {
      const float4 x = ri[k], y = rj[k];
      a += x.x * y.x + x.y * y.y + x.z * y.z + x.w * y.w;
    }
    G4[i * GSTR + j] = a;
    G4[j * GSTR + i] = a;
  }
  __syncthreads();
  // ---- C4. G8 = G4*G4 -> overwrite G2 buffer
  if (tid < 666) {
    int i = 0, rem = tid;
    while (rem >= TDIM - i) { rem -= TDIM - i; ++i; }
    const int j = i + rem;
    const float4* ri = (const float4*)(G4 + i * GSTR);
    const float4* rj = (const float4*)(G4 + j * GSTR);
    float a = 0.0f;
    #pragma unroll
    for (int k = 0; k < GSTR / 4; ++k) {
      const float4 x = ri[k], y = rj[k];
      a += x.x * y.x + x.y * y.y + x.z * y.z + x.w * y.w;
    }
    G2[i * GSTR + j] = a;
    G2[j * GSTR + i] = a;
  }
  __syncthreads();

  // ---- D2. wave 0: power iteration on G8 (renorm every iter) ; others: zero Y+R+Y0
  if (wave == 0) {
    float g8r[36];
    #pragma unroll
    for (int j = 0; j < 36; ++j) g8r[j] = (lane < 36) ? G2[lane * GSTR + j] : 0.0f;
    float v = (lane < 36) ? 1.0f : 0.0f;
    for (int it = 0; it < PITER8; ++it) {
      const int vi = __float_as_int(v);
      float w0 = 0.0f, w1 = 0.0f, w2 = 0.0f, w3 = 0.0f;
      #pragma unroll
      for (int j = 0; j < 36; j += 4) {
        w0 = fmaf(g8r[j],     __int_as_float(__builtin_amdgcn_readlane(vi, j)),     w0);
        w1 = fmaf(g8r[j + 1], __int_as_float(__builtin_amdgcn_readlane(vi, j + 1)), w1);
        w2 = fmaf(g8r[j + 2], __int_as_float(__builtin_amdgcn_readlane(vi, j + 2)), w2);
        w3 = fmaf(g8r[j + 3], __int_as_float(__builtin_amdgcn_readlane(vi, j + 3)), w3);
      }
      float w = (w0 + w1) + (w2 + w3);
      float s = w * w;
      #pragma unroll
      for (int off = 32; off > 0; off >>= 1) s += __shfl_xor(s, off, 64);
      v = w * rsqrtf(s);
    }
    // Rayleigh on ORIGINAL G (v is unit)
    const int vi = __float_as_int(v);
    float w0 = 0.0f, w1 = 0.0f;
    #pragma unroll
    for (int j = 0; j < 36; j += 2) {
      const float gi0 = (lane < 36) ? Gs[lane * GSTR + j]     : 0.0f;
      const float gi1 = (lane < 36) ? Gs[lane * GSTR + j + 1] : 0.0f;
      w0 = fmaf(gi0, __int_as_float(__builtin_amdgcn_readlane(vi, j)),     w0);
      w1 = fmaf(gi1, __int_as_float(__builtin_amdgcn_readlane(vi, j + 1)), w1);
    }
    float num = v * (w0 + w1);
    #pragma unroll
    for (int off = 32; off > 0; off >>= 1) num += __shfl_xor(num, off, 64);
    if (lane == 0) {
      sc[0] = 1.0f / num;        // L_inv
      sc[1] = 0.1f / num;        // thr = lam_f * L_inv
    }
  } else {
    unsigned int* z = (unsigned int*)smc;
    for (int i = tid - 64; i < BY_SC / 4; i += 704) z[i] = 0u;   // Y,R,Y0 zero
  }
  __syncthreads();
  const float L_inv = sc[0];
  const float thr = sc[1];

  float xR[2][2][4], yR[2][2][4];       // [pt-idx][stripe][r]
  #pragma unroll
  for (int k = 0; k < 2; ++k)
    #pragma unroll
    for (int s = 0; s < 2; ++s)
      #pragma unroll
      for (int r = 0; r < 4; ++r) { xR[k][s][r] = 0.0f; yR[k][s][r] = 0.0f; }
  float x0v = 0.0f, y0v = 0.0f;         // constant-atom state (g==5 waves, q<2)

  float tk = 1.0f;

  // ---- F. FISTA loop
  for (int it = 0; it < NITER; ++it) {
    // phase A (all 12 waves): R = Y - D y   (K=160 over atoms 1..160, + scalar y0)
    // Pad rows t>=36 MUST be stored as 0 (colsum reads them).
    {
      const int n0 = 16 * ntA + ln;
      const float y0c = Y0f[n0];
      floatx4 aH0 = {0.f,0.f,0.f,0.f}, aH1 = {0.f,0.f,0.f,0.f};
      floatx4 aL0 = {0.f,0.f,0.f,0.f}, aL1 = {0.f,0.f,0.f,0.f};
      const char* yrow = smc + BY_Y + n0 * YROW;
      #pragma unroll
      for (int ks = 0; ks < NKA; ++ks) {
        const int kb = (32 * ks + 8 * q) * 2;
        const half8 b0 = *(const half8*)(yrow + SWZ(n0, kb));
        if (ks & 1) {
          aH1 = MFMA16(DhF[ks], b0, aH1, 0, 0, 0);
          aL1 = MFMA16(DlF[ks], b0, aL1, 0, 0, 0);
        } else {
          aH0 = MFMA16(DhF[ks], b0, aH0, 0, 0, 0);
          aL0 = MFMA16(DlF[ks], b0, aL0, 0, 0, 0);
        }
      }
      const int t0 = 16 * mtA + 4 * q;
      const bool tval = (t0 < TDIM);    // whole half4 valid or whole half4 pad
      half4 hv;
      #pragma unroll
      for (int r = 0; r < 4; ++r)
        hv[r] = tval ? (half_t)(yA[r] - y0c - ((aH0[r] + aH1[r]) + (aL0[r] + aL1[r])))
                     : (half_t)0.0f;
      *(half4*)(smc + BY_R + n0 * RROW + SWZ(n0, t0 * 2)) = hv;
    }
    __syncthreads();

    const float tnew = 0.5f * (1.0f + sqrtf(1.0f + 4.0f * tk * tk));
    const float ttf = (tk - 1.0f) / tnew;
    tk = tnew;

    // phase B: w = y + L_inv D^T R ; shrink + momentum.
    // Wave reads its 2 nt-stripes of R (4 b128), reused for 2 pt tiles
    // AND (g==5) the constant-atom column-sum (R pads are true zeros now).
    {
      half8 rb[2][2];
      #pragma unroll
      for (int s = 0; s < 2; ++s) {
        const int cS = 16 * (2 * h + s) + ln;
        const char* rrow = smc + BY_R + cS * RROW;
        rb[s][0] = *(const half8*)(rrow + SWZ(cS, 16 * q));        // t = 8q..8q+7
        rb[s][1] = *(const half8*)(rrow + SWZ(cS, 64 + 16 * q));   // t = 32+8q.. (pads 0)
      }

      if (g == 5) {                     // constant atom: row = colsum of R
        float p0 = 0.0f, p1 = 0.0f;
        #pragma unroll
        for (int e = 0; e < 8; ++e) {
          p0 += (float)rb[0][0][e] + (float)rb[0][1][e];
          p1 += (float)rb[1][0][e] + (float)rb[1][1][e];
        }
        p0 += __shfl_xor(p0, 16, 64);  p0 += __shfl_xor(p0, 32, 64);
        p1 += __shfl_xor(p1, 16, 64);  p1 += __shfl_xor(p1, 32, 64);
        if (q < 2) {
          const float part = (q & 1) ? p1 : p0;
          const int cSel = 16 * (2 * h + (q & 1)) + ln;
          const float w = y0v + L_inv * part;
          const float cl = fminf(fmaxf(w, -thr), thr);
          const float xn = w - cl;
          const float yn = xn + ttf * (xn - x0v);
          x0v = xn;
          y0v = yn;
          Y0f[cSel] = yn;
        }
      }

      #pragma unroll
      for (int k = 0; k < 2; ++k) {
        const int pt = g + 6 * k;
        if (pt < 10) {
          #pragma unroll
          for (int s = 0; s < 2; ++s) {
            floatx4 a = {0.f,0.f,0.f,0.f};
            a = MFMA16(DtH[k][0], rb[s][0], a, 0, 0, 0);
            a = MFMA16(DtL[k][0], rb[s][0], a, 0, 0, 0);
            a = MFMA16(DtH[k][1], rb[s][1], a, 0, 0, 0);
            a = MFMA16(DtL[k][1], rb[s][1], a, 0, 0, 0);
            const int cS = 16 * (2 * h + s) + ln;
            const int s0_ = 16 * pt + 4 * q;
            half4 hv;
            #pragma unroll
            for (int r = 0; r < 4; ++r) {
              const float w = yR[k][s][r] + L_inv * a[r];
              const float cl = fminf(fmaxf(w, -thr), thr);   // v_med3 clamp
              const float xn = w - cl;                        // softshrink
              const float yn = xn + ttf * (xn - xR[k][s][r]);
              xR[k][s][r] = xn;
              yR[k][s][r] = yn;
              hv[r] = (half_t)yn;
            }
            *(half4*)(smc + BY_Y + cS * YROW + SWZ(cS, s0_ * 2)) = hv;
          }
        }
      }
    }
    __syncthreads();
  }

  // ---- G. outputs: C = x_fin (atom = slot+1; constant atom from x0v)
  float* Cb = outC + b * PDIM * NCOL;
  #pragma unroll
  for (int k = 0; k < 2; ++k) {
    const int pt = g + 6 * k;
    if (pt < 10) {
      #pragma unroll
      for (int s = 0; s < 2; ++s) {
        const int cS = 16 * (2 * h + s) + ln;
        if (cS < NCOL) {
          #pragma unroll
          for (int r = 0; r < 4; ++r)
            Cb[(16 * pt + 4 * q + r + 1) * NCOL + cS] = xR[k][s][r];
        }
      }
    }
  }
  if (g == 5 && q < 2) {
    const int cSel = 16 * (2 * h + (q & 1)) + ln;
    if (cSel < NCOL) Cb[cSel] = x0v;
  }
  // reconst = D @ C : restage x into Y/Y0, rerun phase-A GEMM with +x0
  #pragma unroll
  for (int k = 0; k < 2; ++k) {
    const int pt = g + 6 * k;
    if (pt < 10) {
      #pragma unroll
      for (int s = 0; s < 2; ++s) {
        const int cS = 16 * (2 * h + s) + ln;
        const int s0_ = 16 * pt + 4 * q;
        half4 hv;
        #pragma unroll
        for (int r = 0; r < 4; ++r) hv[r] = (half_t)xR[k][s][r];
        *(half4*)(smc + BY_Y + cS * YROW + SWZ(cS, s0_ * 2)) = hv;
      }
    }
  }
  if (g == 5 && q < 2) {
    const int cSel = 16 * (2 * h + (q & 1)) + ln;
    Y0f[cSel] = x0v;
  }
  __syncthreads();
  {
    const int n0 = 16 * ntA + ln;
    const float x0c = Y0f[n0];
    floatx4 aH0 = {0.f,0.f,0.f,0.f}, aH1 = {0.f,0.f,0.f,0.f};
    floatx4 aL0 = {0.f,0.f,0.f,0.f}, aL1 = {0.f,0.f,0.f,0.f};
    const char* yrow = smc + BY_Y + n0 * YROW;
    #pragma unroll
    for (int ks = 0; ks < NKA; ++ks) {
      const int kb = (32 * ks + 8 * q) * 2;
      const half8 b0 = *(const half8*)(yrow + SWZ(n0, kb));
      if (ks & 1) {
        aH1 = MFMA16(DhF[ks], b0, aH1, 0, 0, 0);
        aL1 = MFMA16(DlF[ks], b0, aL1, 0, 0, 0);
      } else {
        aH0 = MFMA16(DhF[ks], b0, aH0, 0, 0, 0);
        aL0 = MFMA16(DlF[ks], b0, aL0, 0, 0, 0);
      }
    }
    float* Rb = outR + b * TDIM * NCOL;
    const int c = n0;
    if (c < NCOL) {
      const int t0 = 16 * mtA + 4 * q;
      #pragma unroll
      for (int r = 0; r < 4; ++r) {
        const int t = t0 + r;
        if (t < TDIM)
          Rb[t * NCOL + c] = x0c + (aH0[r] + aH1[r]) + (aL0[r] + aL1[r]);
      }
    }
  }
}

// ---------------- launch --------------------------------------------------------------

extern "C" void kernel_launch(void* const* d_in, const int* in_sizes, int n_in,
                              void* d_out, int out_size, void* d_ws, size_t ws_size,
                              hipStream_t stream) {
  const float* x     = (const float*)d_in[0];   // (256, 36, 50)
  const float* rho   = (const float*)d_in[1];   // (80,)
  const float* theta = (const float*)d_in[2];   // (80,)

  float* out    = (float*)d_out;
  float* outC   = out;                              // 256*161*50
  float* outDic = out + 256 * PDIM * NCOL;          // 36*161
  float* outR   = outDic + TDIM * PDIM;             // 256*36*50

  hipLaunchKernelGGL(dan_kernel, dim3(256), dim3(768), LDS_TOTAL, stream,
                     x, rho, theta, outC, outDic, outR);
}

// Round 8
// 210.908 us; speedup vs baseline: 1.1660x; 1.1660x over previous
//
#include <hip/hip_runtime.h>
#include <math.h>

typedef _Float16 half_t;
typedef __attribute__((ext_vector_type(8))) _Float16 half8;
typedef __attribute__((ext_vector_type(4))) _Float16 half4;
typedef __attribute__((ext_vector_type(4))) float floatx4;

#define TDIM 36
#define PDIM 161        // 2*80+1 atoms
#define NCOL 50
#define NITER 100
#define PITER8 50       // power steps on G^8 == 400 on G (same total as proven config)

// R4 structure (190 us proven) + phase-B 2pt x 2stripe remap + Dt hi-only.
// phase A: M=48,N=64,K=192 (6 ks), 12 waves = 3 mt x 4 nt, D in hi/lo (12 MFMA)
// phase B: M=192 (12 pt incl. ghost pt=11 over zero atoms), N=64, K=64;
//          wave (g=w>>1,h=w&1) owns pt in {g,g+6}, stripes {2h,2h+1};
//          D^T hi ONLY (error scales with the shrinking residual) -> 8 MFMA/wave.
#define NKA 6
#define GSTR 44
#define SPS 196         // Df (fp32) row stride (dwords)

// row strides in BYTES
#define YROW 384        // y^T [64][192] half
#define RROW 128        // R^T [64][64] half

// XOR swizzle: spread same-column reads across 8 rows -> 8 distinct 16B slots
#define SWZ(row, byteoff) ((byteoff) ^ (((row) & 7) << 4))

// ---- byte-offset LDS map: 51,792 B ----
#define BY_Y    0                      // 24,576
#define BY_R    24576                  //  8,192
#define BY_LRTH 28672                  //  1,288 (inside R region, past Df end 28,224)
#define BY_SC   32768                  //     16
#define BY_GS   32784                  //  6,336
#define BY_G2   39120                  //  6,336  (holds G^2, later overwritten by G^8)
#define BY_G4   45456                  //  6,336
#define LDS_TOTAL 51792
// setup alias: Df fp32 [36][196] = 28,224 B over Y + head of R (re-zeroed before loop)

#define MFMA16 __builtin_amdgcn_mfma_f32_16x16x32_f16

__global__ __launch_bounds__(768, 3)
void dan_kernel(const float* __restrict__ xin, const float* __restrict__ rho,
                const float* __restrict__ theta, float* __restrict__ outC,
                float* __restrict__ outDic, float* __restrict__ outR)
{
  extern __shared__ char smc[];
  float*  sc   = (float*)(smc + BY_SC);
  float*  Gs   = (float*)(smc + BY_GS);
  float*  G2   = (float*)(smc + BY_G2);
  float*  G4   = (float*)(smc + BY_G4);
  float*  Df   = (float*)(smc + BY_Y);    // setup alias
  float*  lrth = (float*)(smc + BY_LRTH); // [161] lr, [161] th (setup only)

  const int tid = threadIdx.x;
  const int b = blockIdx.x;
  const int wave = tid >> 6, lane = tid & 63;
  const int q = lane >> 4, ln = lane & 15;

  // ---- A. zero all LDS (pads must be 0)
  {
    unsigned int* z = (unsigned int*)smc;
    for (int i = tid; i < LDS_TOTAL / 4; i += 768) z[i] = 0u;
  }
  __syncthreads();

  // ---- B0. per-atom lr/th (161 threads, 2 transcendentals each)
  if (tid >= 1 && tid < PDIM) {
    const bool is_sin = tid > 80;
    const int n = is_sin ? (tid - 81) : (tid - 1);
    lrth[tid]       = logf(0.001f + 1.149f / (1.0f + expf(-rho[n])));
    lrth[161 + tid] = 3.14159265358979f / (1.0f + expf(-theta[n]));
  }
  __syncthreads();

  // ---- B1. raw dictionary, parallel over all (t,p) jobs
  for (int i = tid; i < TDIM * PDIM; i += 768) {
    const int t = i / PDIM, p = i - t * PDIM;
    float val;
    if (p == 0) {
      val = 1.0f;
    } else {
      const float ft = (float)t;
      const float e = expf(ft * lrth[p]);
      const float ang = ft * lrth[161 + p];
      val = e * (p > 80 ? sinf(ang) : cosf(ang));
    }
    Df[t * SPS + p] = val;
  }
  __syncthreads();

  // ---- B2. column-normalize (atoms 1..160)
  if (tid >= 1 && tid < PDIM) {
    float s2 = 0.0f;
    for (int t = 0; t < TDIM; ++t) {
      const float v = Df[t * SPS + tid];
      s2 += v * v;
    }
    const float inv = 1.0f / sqrtf(s2);
    for (int t = 0; t < TDIM; ++t) Df[t * SPS + tid] *= inv;
  }
  __syncthreads();

  // ---- C. Gram -> Gs ; dic out ; load ALL MFMA fragments to registers
  if (tid < 666) {                      // 666 = 36*37/2
    int i = 0, rem = tid;
    while (rem >= TDIM - i) { rem -= TDIM - i; ++i; }
    const int j = i + rem;
    const float4* ri = (const float4*)(Df + i * SPS);
    const float4* rj = (const float4*)(Df + j * SPS);
    float a = 0.0f;
    #pragma unroll 7
    for (int k = 0; k < SPS / 4; ++k) {
      const float4 x = ri[k], y = rj[k];
      a += x.x * y.x + x.y * y.y + x.z * y.z + x.w * y.w;
    }
    Gs[i * GSTR + j] = a;
    Gs[j * GSTR + i] = a;
  }
  if (b == 0) {
    for (int i = tid; i < TDIM * PDIM; i += 768) {
      const int t = i / PDIM, p = i - t * PDIM;
      outDic[i] = Df[t * SPS + p];
    }
  }

  // ownership maps
  const int mtA = wave >> 2;            // phase A: 3 mt x 4 nt, one tile per wave
  const int ntA = wave & 3;
  const int g = wave >> 1;              // phase B: pt in {g, g+6} (pt=11 = ghost)
  const int h = wave & 1;               //          stripes {2h, 2h+1}

  // phase-A A-fragments (D hi/lo); rows >= 36 are zero (Df region zero there)
  half8 DhF[NKA], DlF[NKA];
  {
    const int row = 16 * mtA + ln;
    #pragma unroll
    for (int ks = 0; ks < NKA; ++ks) {
      half8 hh = {0,0,0,0,0,0,0,0}, ll = {0,0,0,0,0,0,0,0};
      if (row < TDIM) {
        const float4 f0 = *(const float4*)(Df + row * SPS + 32 * ks + 8 * q);
        const float4 f1 = *(const float4*)(Df + row * SPS + 32 * ks + 8 * q + 4);
        const float fa[8] = {f0.x, f0.y, f0.z, f0.w, f1.x, f1.y, f1.z, f1.w};
        #pragma unroll
        for (int e = 0; e < 8; ++e) {
          const half_t h2 = (half_t)fa[e];
          hh[e] = h2;
          ll[e] = (half_t)(fa[e] - (float)h2);
        }
      }
      DhF[ks] = hh;
      DlF[ks] = ll;
    }
  }
  // phase-B A-fragments (D^T hi ONLY), transposed read from Df; atoms>=161 zero
  half8 DtH[2][2];                      // [k][ks]
  #pragma unroll
  for (int k = 0; k < 2; ++k) {
    const int atom = 16 * (g + 6 * k) + ln;         // 0..191 (>=161 -> zero cols)
    #pragma unroll
    for (int ks = 0; ks < 2; ++ks) {
      half8 hh;
      #pragma unroll
      for (int e = 0; e < 8; ++e) {
        const int t = 32 * ks + 8 * q + e;
        const float v = (t < TDIM) ? Df[t * SPS + atom] : 0.0f;
        hh[e] = (half_t)v;
      }
      DtH[k][ks] = hh;
    }
  }
  // static Y (fp32) at phase-A C positions
  float yA[4];
  {
    const float* xb = xin + b * TDIM * NCOL;
    const int c = 16 * ntA + ln;
    #pragma unroll
    for (int r = 0; r < 4; ++r) {
      const int t = 16 * mtA + 4 * q + r;
      yA[r] = (t < TDIM && c < NCOL) ? xb[t * NCOL + c] : 0.0f;
    }
  }
  __syncthreads();

  // ---- C2. G2 = G*G  (pads of all Gram buffers are zero)
  if (tid < 666) {
    int i = 0, rem = tid;
    while (rem >= TDIM - i) { rem -= TDIM - i; ++i; }
    const int j = i + rem;
    const float4* ri = (const float4*)(Gs + i * GSTR);
    const float4* rj = (const float4*)(Gs + j * GSTR);
    float a = 0.0f;
    #pragma unroll
    for (int k = 0; k < GSTR / 4; ++k) {
      const float4 x = ri[k], y = rj[k];
      a += x.x * y.x + x.y * y.y + x.z * y.z + x.w * y.w;
    }
    G2[i * GSTR + j] = a;
    G2[j * GSTR + i] = a;
  }
  __syncthreads();
  // ---- C3. G4 = G2*G2
  if (tid < 666) {
    int i = 0, rem = tid;
    while (rem >= TDIM - i) { rem -= TDIM - i; ++i; }
    const int j = i + rem;
    const float4* ri = (const float4*)(G2 + i * GSTR);
    const float4* rj = (const float4*)(G2 + j * GSTR);
    float a = 0.0f;
    #pragma unroll
    for (int k = 0; k < GSTR / 4; ++k) {
      const float4 x = ri[k], y = rj[k];
      a += x.x * y.x + x.y * y.y + x.z * y.z + x.w * y.w;
    }
    G4[i * GSTR + j] = a;
    G4[j * GSTR + i] = a;
  }
  __syncthreads();
  // ---- C4. G8 = G4*G4 -> overwrite G2 buffer
  if (tid < 666) {
    int i = 0, rem = tid;
    while (rem >= TDIM - i) { rem -= TDIM - i; ++i; }
    const int j = i + rem;
    const float4* ri = (const float4*)(G4 + i * GSTR);
    const float4* rj = (const float4*)(G4 + j * GSTR);
    float a = 0.0f;
    #pragma unroll
    for (int k = 0; k < GSTR / 4; ++k) {
      const float4 x = ri[k], y = rj[k];
      a += x.x * y.x + x.y * y.y + x.z * y.z + x.w * y.w;
    }
    G2[i * GSTR + j] = a;
    G2[j * GSTR + i] = a;
  }
  __syncthreads();

  // ---- D2. wave 0: power iteration on G8 (renorm every iter) ; others: zero Y+R
  if (wave == 0) {
    float g8r[36];
    #pragma unroll
    for (int j = 0; j < 36; ++j) g8r[j] = (lane < 36) ? G2[lane * GSTR + j] : 0.0f;
    float v = (lane < 36) ? 1.0f : 0.0f;
    for (int it = 0; it < PITER8; ++it) {
      const int vi = __float_as_int(v);
      float w0 = 0.0f, w1 = 0.0f, w2 = 0.0f, w3 = 0.0f;
      #pragma unroll
      for (int j = 0; j < 36; j += 4) {
        w0 = fmaf(g8r[j],     __int_as_float(__builtin_amdgcn_readlane(vi, j)),     w0);
        w1 = fmaf(g8r[j + 1], __int_as_float(__builtin_amdgcn_readlane(vi, j + 1)), w1);
        w2 = fmaf(g8r[j + 2], __int_as_float(__builtin_amdgcn_readlane(vi, j + 2)), w2);
        w3 = fmaf(g8r[j + 3], __int_as_float(__builtin_amdgcn_readlane(vi, j + 3)), w3);
      }
      float w = (w0 + w1) + (w2 + w3);
      float s = w * w;
      #pragma unroll
      for (int off = 32; off > 0; off >>= 1) s += __shfl_xor(s, off, 64);
      v = w * rsqrtf(s);
    }
    // Rayleigh on ORIGINAL G (v is unit)
    const int vi = __float_as_int(v);
    float w0 = 0.0f, w1 = 0.0f;
    #pragma unroll
    for (int j = 0; j < 36; j += 2) {
      const float gi0 = (lane < 36) ? Gs[lane * GSTR + j]     : 0.0f;
      const float gi1 = (lane < 36) ? Gs[lane * GSTR + j + 1] : 0.0f;
      w0 = fmaf(gi0, __int_as_float(__builtin_amdgcn_readlane(vi, j)),     w0);
      w1 = fmaf(gi1, __int_as_float(__builtin_amdgcn_readlane(vi, j + 1)), w1);
    }
    float num = v * (w0 + w1);
    #pragma unroll
    for (int off = 32; off > 0; off >>= 1) num += __shfl_xor(num, off, 64);
    if (lane == 0) {
      sc[0] = 1.0f / num;        // L_inv
      sc[1] = 0.1f / num;        // thr = lam_f * L_inv
    }
  } else {
    unsigned int* z = (unsigned int*)smc;
    for (int i = tid - 64; i < 32768 / 4; i += 704) z[i] = 0u;   // kill Df alias; y0=0
  }
  __syncthreads();
  const float L_inv = sc[0];
  const float thr = sc[1];

  float xR[2][2][4], yR[2][2][4];       // [pt-idx][stripe][r]
  #pragma unroll
  for (int k = 0; k < 2; ++k)
    #pragma unroll
    for (int s = 0; s < 2; ++s)
      #pragma unroll
      for (int r = 0; r < 4; ++r) { xR[k][s][r] = 0.0f; yR[k][s][r] = 0.0f; }

  float tk = 1.0f;

  // ---- F. FISTA loop (R4 phase A; remapped hi-only phase B)
  for (int it = 0; it < NITER; ++it) {
    // phase A (all 12 waves): R = Y - D y   (M=48, N=64, K=192)
    {
      floatx4 aH0 = {0.f,0.f,0.f,0.f}, aH1 = {0.f,0.f,0.f,0.f};
      floatx4 aL0 = {0.f,0.f,0.f,0.f}, aL1 = {0.f,0.f,0.f,0.f};
      const int n0 = 16 * ntA + ln;
      const char* yrow = smc + BY_Y + n0 * YROW;
      #pragma unroll
      for (int ks = 0; ks < NKA; ++ks) {
        const int kb = (32 * ks + 8 * q) * 2;
        const half8 b0 = *(const half8*)(yrow + SWZ(n0, kb));
        if (ks & 1) {
          aH1 = MFMA16(DhF[ks], b0, aH1, 0, 0, 0);
          aL1 = MFMA16(DlF[ks], b0, aL1, 0, 0, 0);
        } else {
          aH0 = MFMA16(DhF[ks], b0, aH0, 0, 0, 0);
          aL0 = MFMA16(DlF[ks], b0, aL0, 0, 0, 0);
        }
      }
      const int t0 = 16 * mtA + 4 * q;
      half4 hv;
      #pragma unroll
      for (int r = 0; r < 4; ++r)
        hv[r] = (half_t)(yA[r] - ((aH0[r] + aH1[r]) + (aL0[r] + aL1[r])));
      *(half4*)(smc + BY_R + n0 * RROW + SWZ(n0, t0 * 2)) = hv;
    }
    __syncthreads();

    const float tnew = 0.5f * (1.0f + sqrtf(1.0f + 4.0f * tk * tk));
    const float ttf = (tk - 1.0f) / tnew;
    tk = tnew;

    // phase B: w = y + L_inv D^T R ; shrink + momentum  (hi-only D^T)
    // Wave reads its 2 nt-stripes of R (4 b128), reused for its 2 pt tiles.
    {
      half8 rb[2][2];
      #pragma unroll
      for (int s = 0; s < 2; ++s) {
        const int cS = 16 * (2 * h + s) + ln;
        const char* rrow = smc + BY_R + cS * RROW;
        rb[s][0] = *(const half8*)(rrow + SWZ(cS, 16 * q));        // t = 8q..8q+7
        rb[s][1] = *(const half8*)(rrow + SWZ(cS, 64 + 16 * q));   // t = 32+8q.. (pads 0)
      }

      #pragma unroll
      for (int k = 0; k < 2; ++k) {
        const int pt = g + 6 * k;
        const int p0 = 16 * pt + 4 * q;
        #pragma unroll
        for (int s = 0; s < 2; ++s) {
          floatx4 a = {0.f,0.f,0.f,0.f};
          a = MFMA16(DtH[k][0], rb[s][0], a, 0, 0, 0);
          a = MFMA16(DtH[k][1], rb[s][1], a, 0, 0, 0);
          const int cS = 16 * (2 * h + s) + ln;
          half4 hv;
          #pragma unroll
          for (int r = 0; r < 4; ++r) {
            const float w = yR[k][s][r] + L_inv * a[r];
            const float cl = fminf(fmaxf(w, -thr), thr);   // v_med3 clamp
            const float xn = w - cl;                        // softshrink
            const float yn = xn + ttf * (xn - xR[k][s][r]);
            xR[k][s][r] = xn;
            yR[k][s][r] = yn;
            hv[r] = (half_t)yn;
          }
          *(half4*)(smc + BY_Y + cS * YROW + SWZ(cS, p0 * 2)) = hv;
        }
      }
    }
    __syncthreads();
  }

  // ---- G. outputs: C = x_fin (ghost pt=11 masked by p<PDIM)
  float* Cb = outC + b * PDIM * NCOL;
  #pragma unroll
  for (int k = 0; k < 2; ++k) {
    const int pt = g + 6 * k;
    #pragma unroll
    for (int s = 0; s < 2; ++s) {
      const int cS = 16 * (2 * h + s) + ln;
      if (cS < NCOL) {
        #pragma unroll
        for (int r = 0; r < 4; ++r) {
          const int p = 16 * pt + 4 * q + r;
          if (p < PDIM) Cb[p * NCOL + cS] = xR[k][s][r];
        }
      }
    }
  }
  // reconst = D @ C : restage x into Y (fp16), rerun phase-A GEMM
  #pragma unroll
  for (int k = 0; k < 2; ++k) {
    const int pt = g + 6 * k;
    const int p0 = 16 * pt + 4 * q;
    #pragma unroll
    for (int s = 0; s < 2; ++s) {
      const int cS = 16 * (2 * h + s) + ln;
      half4 hv;
      #pragma unroll
      for (int r = 0; r < 4; ++r) hv[r] = (half_t)xR[k][s][r];
      *(half4*)(smc + BY_Y + cS * YROW + SWZ(cS, p0 * 2)) = hv;
    }
  }
  __syncthreads();
  {
    floatx4 aH0 = {0.f,0.f,0.f,0.f}, aH1 = {0.f,0.f,0.f,0.f};
    floatx4 aL0 = {0.f,0.f,0.f,0.f}, aL1 = {0.f,0.f,0.f,0.f};
    const int n0 = 16 * ntA + ln;
    const char* yrow = smc + BY_Y + n0 * YROW;
    #pragma unroll
    for (int ks = 0; ks < NKA; ++ks) {
      const int kb = (32 * ks + 8 * q) * 2;
      const half8 b0 = *(const half8*)(yrow + SWZ(n0, kb));
      if (ks & 1) {
        aH1 = MFMA16(DhF[ks], b0, aH1, 0, 0, 0);
        aL1 = MFMA16(DlF[ks], b0, aL1, 0, 0, 0);
      } else {
        aH0 = MFMA16(DhF[ks], b0, aH0, 0, 0, 0);
        aL0 = MFMA16(DlF[ks], b0, aL0, 0, 0, 0);
      }
    }
    float* Rb = outR + b * TDIM * NCOL;
    const int c = n0;
    if (c < NCOL) {
      const int t0 = 16 * mtA + 4 * q;
      #pragma unroll
      for (int r = 0; r < 4; ++r) {
        const int t = t0 + r;
        if (t < TDIM)
          Rb[t * NCOL + c] = (aH0[r] + aH1[r]) + (aL0[r] + aL1[r]);
      }
    }
  }
}

// ---------------- launch --------------------------------------------------------------

extern "C" void kernel_launch(void* const* d_in, const int* in_sizes, int n_in,
                              void* d_out, int out_size, void* d_ws, size_t ws_size,
                              hipStream_t stream) {
  const float* x     = (const float*)d_in[0];   // (256, 36, 50)
  const float* rho   = (const float*)d_in[1];   // (80,)
  const float* theta = (const float*)d_in[2];   // (80,)

  float* out    = (float*)d_out;
  float* outC   = out;                              // 256*161*50
  float* outDic = out + 256 * PDIM * NCOL;          // 36*161
  float* outR   = outDic + TDIM * PDIM;             // 256*36*50

  hipLaunchKernelGGL(dan_kernel, dim3(256), dim3(768), LDS_TOTAL, stream,
                     x, rho, theta, outC, outDic, outR);
}